// Round 4
// baseline (606.632 us; speedup 1.0000x reference)
//
#include <hip/hip_runtime.h>

#define IN_C 512
#define OUT_C 512
#define BATCH 16
#define NPX 4096   // 64*64

using bf16x8 = __attribute__((ext_vector_type(8))) __bf16;
using f32x4  = __attribute__((ext_vector_type(4))) float;

static constexpr float kConvScale = 0.014731391274719739f; // 1/sqrt(512*9)
static constexpr float kModScale  = 0.04419417382415922f;  // 1/sqrt(512)
static constexpr float kEps       = 1e-8f;

#define WT_TILE_BYTES (9 * 128 * 64)   // 73728 B per (ics, ot) weight tile

// ---------- 1) s[b][ic] = style[b,:] . mod_weight[ic,:] * MOD_SCALE + mod_bias[ic]
__global__ void style_k(const float* __restrict__ style, const float* __restrict__ mw,
                        const float* __restrict__ mb, float* __restrict__ s) {
  __shared__ float st[IN_C];
  const int b = blockIdx.x, t = threadIdx.x;   // 512 threads
  st[t] = style[b * IN_C + t];
  __syncthreads();
  const float4* row = (const float4*)(mw + (size_t)t * IN_C);
  float acc = 0.f;
  #pragma unroll 4
  for (int i = 0; i < IN_C / 4; i++) {
    float4 v = row[i];
    float4 u = *(const float4*)(st + i * 4);
    acc += v.x * u.x + v.y * u.y + v.z * u.z + v.w * u.w;
  }
  s[b * IN_C + t] = acc * kModScale + mb[t];
}

// ---------- 2) wsq[oc][ic] = sum_tap w^2 ; wsw = bf16 weights, tile-major + XOR-swizzled
// Tile (ics, ot): logical byte B = (tap*128 + oc_local)*64 + ic_local*2,
// stored at B ^ (((B>>7)&7)<<4).
__global__ void wprep_k(const float* __restrict__ w, float* __restrict__ wsq,
                        char* __restrict__ wsw) {
  const int idx = blockIdx.x * 256 + threadIdx.x;  // 262144 total
  const int ic = idx & (IN_C - 1), oc = idx >> 9;
  const int ot = oc >> 7, ocl = oc & 127, ics = ic >> 5, icl = ic & 31;
  char* tile = wsw + (size_t)(ics * 4 + ot) * WT_TILE_BYTES;
  const float* p = w + (size_t)(oc * IN_C + ic) * 9;
  float q = 0.f;
  #pragma unroll
  for (int t = 0; t < 9; t++) {
    float v = p[t];
    q += v * v;
    int B = ((t * 128 + ocl) << 6) + icl * 2;
    int Bsw = B ^ (((B >> 7) & 7) << 4);
    *(__bf16*)(tile + Bsw) = (__bf16)v;
  }
  wsq[oc * IN_C + ic] = q;
}

// ---------- 3) dscale[b][oc] = CONV_SCALE * rsqrt(CONV_SCALE^2 * sum_ic s^2*wsq + eps)
__global__ void demod_k(const float* __restrict__ s, const float* __restrict__ wsq,
                        float* __restrict__ dsc) {
  __shared__ float s2[IN_C];
  const int b = blockIdx.x, t = threadIdx.x;   // 512 threads
  float sv = s[b * IN_C + t];
  s2[t] = sv * sv;
  __syncthreads();
  const float4* row = (const float4*)(wsq + (size_t)t * IN_C);
  float acc = 0.f;
  #pragma unroll 4
  for (int i = 0; i < IN_C / 4; i++) {
    float4 v = row[i];
    float4 u = *(const float4*)(s2 + i * 4);
    acc += v.x * u.x + v.y * u.y + v.z * u.z + v.w * u.w;
  }
  dsc[b * OUT_C + t] = kConvScale * rsqrtf(kConvScale * kConvScale * acc + kEps);
}

// ---------- 4) xmod[b][p][ic] = bf16(x[b][ic][p] * s[b][ic])   (NCHW -> NHWC transpose)
__global__ void modx_k(const float* __restrict__ x, const float* __restrict__ s,
                       __bf16* __restrict__ xm) {
  __shared__ __bf16 tile[64][73];
  const int t = threadIdx.x;                   // 256 threads
  const int bid = blockIdx.x;                  // 16 * 8 * 64
  const int ict = bid & 7, pt = (bid >> 3) & 63, b = bid >> 9;
  const int ic0 = ict * 64, p0 = pt * 64;
  #pragma unroll
  for (int it = 0; it < 16; it++) {
    int idx = it * 256 + t;
    int pl = idx & 63, icl = idx >> 6;
    int ic = ic0 + icl;
    float v = x[((size_t)b * IN_C + ic) * NPX + p0 + pl] * s[b * IN_C + ic];
    tile[icl][pl] = (__bf16)v;
  }
  __syncthreads();
  #pragma unroll
  for (int it = 0; it < 2; it++) {
    int idx = it * 256 + t;
    int icb = idx & 7, pl = idx >> 3;
    alignas(16) __bf16 tmp[8];
    #pragma unroll
    for (int j = 0; j < 8; j++) tmp[j] = tile[icb * 8 + j][pl];
    *(uint4*)(xm + ((size_t)b * NPX + p0 + pl) * IN_C + ic0 + icb * 8) = *(const uint4*)tmp;
  }
}

// ---------- 5) conv: NEW this round — 4-wave blocks (256 thr), 1 wave/SIMD,
// wave-tile 128oc x 128px, acc[8][8] f32x4 = 256 regs (512-reg budget at 1 wave/EU).
// Rationale (corrected model): per-SIMD MFMA cost is ~19.4 cyc/mfma -> round-0's
// step was ~11.2K cyc MFMA + ~10.4K LDS reads (864 KB) imperfectly overlapped (19K).
// This tiling cuts LDS reads to 576 KB/step (A no longer 4x-duplicated across
// waves) so LDS (~6-7K) fits under the MFMA wall. Input staging via
// global_load_lds (NHWC -> LDS dest linear in tid; unpadded [10][66][32ic] rows),
// x double-buffered (84.5 KB) so next-step x transfers ride under compute and
// drain for free at the next barrier. Weights single-buffered (73.7 KB; LDS
// total 158.2 KB, 1 block/CU): only the w-drain (~1K cyc) stays exposed.
// Plain __syncthreads only — rounds 1/2 proved asm waits/sched_barrier(0) spill.

#define XROW 4224              // 66 slots * 64 B (32 ic * 2 B), no pad
#define XBUF 42240             // 10 rows * XROW

#define SGB __builtin_amdgcn_sched_group_barrier
// per tap: 16 DS_READ + 64 MFMA -> interleave {2 DS, 8 MFMA} x8
#define SGB_MIX() { SGB(0x100, 2, 0); SGB(0x8, 8, 0); SGB(0x100, 2, 0); SGB(0x8, 8, 0); \
                    SGB(0x100, 2, 0); SGB(0x8, 8, 0); SGB(0x100, 2, 0); SGB(0x8, 8, 0); \
                    SGB(0x100, 2, 0); SGB(0x8, 8, 0); SGB(0x100, 2, 0); SGB(0x8, 8, 0); \
                    SGB(0x100, 2, 0); SGB(0x8, 8, 0); SGB(0x100, 2, 0); SGB(0x8, 8, 0); }
#define SGB_MFMA() { SGB(0x8, 8, 0); SGB(0x8, 8, 0); SGB(0x8, 8, 0); SGB(0x8, 8, 0); \
                     SGB(0x8, 8, 0); SGB(0x8, 8, 0); SGB(0x8, 8, 0); SGB(0x8, 8, 0); }

__global__ __launch_bounds__(256, 1)
void conv_k(const __bf16* __restrict__ xm, const char* __restrict__ wsw,
            const float* __restrict__ dsc, float* __restrict__ out) {
  __shared__ __align__(16) char xsb[2 * XBUF];        // 84480 B, double-buffered input
  __shared__ __align__(16) char wsb[WT_TILE_BYTES];   // 73728 B, weight tile

  const int tid = threadIdx.x;
  const int lane = tid & 63;
  const int wn = tid >> 6;                 // 4 waves = 4 px-quarters (128 px each)
  const int l15 = lane & 15, kb8 = lane >> 4;
  const int bid = blockIdx.x;
  const int pt = bid & 7, ot = (bid >> 3) & 3, b = bid >> 5;
  const int h0 = pt * 8, oc0 = ot * 128;

  // zero halo columns (slots 0 and 65), all 10 rows, BOTH buffers; never overwritten
  if (tid < 160) {
    int bb = tid / 80, rr = (tid % 80) >> 3, side = (tid >> 2) & 1, ch = tid & 3;
    uint4 z = {0, 0, 0, 0};
    *(uint4*)(xsb + bb * XBUF + rr * XROW + side * 65 * 64 + ch * 16) = z;
  }
  // zero halo rows for edge blocks (rows skipped by XGLDS stay zero all steps)
  if (h0 == 0) {
    uint4 z = {0, 0, 0, 0};
    for (int i = tid; i < 2 * 264; i += 256)
      *((uint4*)(xsb + (i >= 264 ? XBUF : 0)) + (i % 264)) = z;
  }
  if (h0 == 56) {
    uint4 z = {0, 0, 0, 0};
    for (int i = tid; i < 2 * 264; i += 256)
      *((uint4*)(xsb + (i >= 264 ? XBUF : 0) + 9 * XROW) + (i % 264)) = z;
  }

  // ---- input staging: one glds per row; dest linear in tid (row interior = 4 KB);
  // source NHWC per-lane. h-guard is wave-uniform (r compile-time, h0 block-uniform).
  #define XGLDS(ICS, BUF)                                                     \
    {                                                                         \
      _Pragma("unroll")                                                       \
      for (int r = 0; r < 10; r++) {                                          \
        int h = h0 + r - 1;                                                   \
        if ((unsigned)h < 64u)                                                \
          __builtin_amdgcn_global_load_lds(                                   \
              (const __attribute__((address_space(1))) void*)(xm +            \
                  ((size_t)(b * 4096 + h * 64 + (tid >> 2))) * 512 +          \
                  (ICS) * 32 + (tid & 3) * 8),                                \
              (__attribute__((address_space(3))) void*)(xsb + (BUF) +         \
                  r * XROW + 64 + tid * 16),                                  \
              16, 0, 0);                                                      \
      }                                                                       \
    }
  // ---- weight staging: 18 glds/thread, linear, source pre-swizzled
  #define WGLDS(ICS)                                                          \
    {                                                                         \
      const char* wt = wsw + (size_t)((ICS) * 4 + ot) * WT_TILE_BYTES;        \
      _Pragma("unroll")                                                       \
      for (int g = 0; g < 18; g++) {                                          \
        int off = (g * 256 + tid) * 16;                                       \
        __builtin_amdgcn_global_load_lds(                                     \
            (const __attribute__((address_space(1))) void*)(wt + off),        \
            (__attribute__((address_space(3))) void*)(wsb + off), 16, 0, 0);  \
      }                                                                       \
    }

  f32x4 acc[8][8];
  #pragma unroll
  for (int i = 0; i < 8; i++)
    #pragma unroll
    for (int j = 0; j < 8; j++) acc[i][j] = f32x4{0.f, 0.f, 0.f, 0.f};

  // swizzled weight read address: oc_local = fm*16 + l15; fm*16>>1 == 0 (mod 8),
  // so the XOR mask depends only on l15 — same swizzle for all 8 fm.
  const int swz = ((l15 >> 1) & 7) << 4;
  const int wrd_base = ((l15 << 6) + kb8 * 16) ^ swz;

  // per-fn x-tile byte offsets (px window of this wave; +1 halo col is dx-implicit)
  int xoff[8];
  #pragma unroll
  for (int fn = 0; fn < 8; fn++) {
    int px = wn * 128 + fn * 16 + l15;
    xoff[fn] = (px >> 6) * XROW + (px & 63) * 64 + kb8 * 16;
  }

  bf16x8 afA[8], bfA[8], afB[8], bfB[8];
  #define LOADT(T, AF, BF)                                                    \
    {                                                                         \
      _Pragma("unroll")                                                       \
      for (int fm = 0; fm < 8; fm++)                                          \
        AF[fm] = *(const bf16x8*)(wsb + ((T) * 8192 + fm * 1024 + wrd_base)); \
      _Pragma("unroll")                                                       \
      for (int fn = 0; fn < 8; fn++)                                          \
        BF[fn] = *(const bf16x8*)(xcur + xoff[fn] + ((T) / 3) * XROW +        \
                                  ((T) % 3) * 64);                            \
    }
  #define MFMAT(AF, BF)                                                       \
    {                                                                         \
      _Pragma("unroll")                                                       \
      for (int fm = 0; fm < 8; fm++)                                          \
        _Pragma("unroll")                                                     \
        for (int fn = 0; fn < 8; fn++)                                        \
          acc[fm][fn] = __builtin_amdgcn_mfma_f32_16x16x32_bf16(              \
              AF[fm], BF[fn], acc[fm][fn], 0, 0, 0);                          \
    }

  XGLDS(0, 0)

  for (int s = 0; s < 16; s++) {
    const char* xcur = xsb + (s & 1) * XBUF;
    __syncthreads();                       // (a) prev compute done; drains x(s) glds
    WGLDS(s)
    __syncthreads();                       // (b) drains w(s) -> weights resident
    if (s < 15) XGLDS(s + 1, ((s + 1) & 1) * XBUF)   // rides under compute

    LOADT(0, afA, bfA)
    LOADT(1, afB, bfB)
    MFMAT(afA, bfA)  SGB_MIX()             // t0 (overlaps t1 loads issued above)
    LOADT(2, afA, bfA)
    MFMAT(afB, bfB)  SGB_MIX()             // t1 || load t2
    LOADT(3, afB, bfB)
    MFMAT(afA, bfA)  SGB_MIX()             // t2 || load t3
    LOADT(4, afA, bfA)
    MFMAT(afB, bfB)  SGB_MIX()             // t3 || load t4
    LOADT(5, afB, bfB)
    MFMAT(afA, bfA)  SGB_MIX()             // t4 || load t5
    LOADT(6, afA, bfA)
    MFMAT(afB, bfB)  SGB_MIX()             // t5 || load t6
    LOADT(7, afB, bfB)
    MFMAT(afA, bfA)  SGB_MIX()             // t6 || load t7
    LOADT(8, afA, bfA)
    MFMAT(afB, bfB)  SGB_MIX()             // t7 || load t8
    MFMAT(afA, bfA)  SGB_MFMA()            // t8
  }

  // epilogue: D row = oc_local (= fm*16 + kb8*4 + j), col = px (= wn*128 + fn*16 + l15)
  #pragma unroll
  for (int fm = 0; fm < 8; fm++) {
    #pragma unroll
    for (int j = 0; j < 4; j++) {
      int oc = oc0 + fm * 16 + kb8 * 4 + j;
      float dm = dsc[b * OUT_C + oc];
      float* orow = out + ((size_t)b * OUT_C + oc) * NPX + h0 * 64;
      #pragma unroll
      for (int fn = 0; fn < 8; fn++) {
        int px = wn * 128 + fn * 16 + l15;
        orow[px] = acc[fm][fn][j] * dm;
      }
    }
  }
}

extern "C" void kernel_launch(void* const* d_in, const int* in_sizes, int n_in,
                              void* d_out, int out_size, void* d_ws, size_t ws_size,
                              hipStream_t stream) {
  const float* input  = (const float*)d_in[0];
  const float* style  = (const float*)d_in[1];
  const float* weight = (const float*)d_in[2];
  const float* mod_w  = (const float*)d_in[3];
  const float* mod_b  = (const float*)d_in[4];
  float* out = (float*)d_out;

  char* p = (char*)d_ws;
  float* s    = (float*)p;  p += (size_t)BATCH * IN_C * 4;       // 32 KB
  float* dsc  = (float*)p;  p += (size_t)BATCH * OUT_C * 4;      // 32 KB
  float* wsq  = (float*)p;  p += (size_t)OUT_C * IN_C * 4;       // 1 MB
  char*  wsw  = p;          p += (size_t)16 * 4 * WT_TILE_BYTES; // 4.5 MB
  __bf16* xm  = (__bf16*)p;                                      // 64 MB

  style_k<<<BATCH, 512, 0, stream>>>(style, mod_w, mod_b, s);
  wprep_k<<<1024, 256, 0, stream>>>(weight, wsq, wsw);
  demod_k<<<BATCH, 512, 0, stream>>>(s, wsq, dsc);
  modx_k<<<BATCH * 8 * 64, 256, 0, stream>>>(input, s, xm);
  conv_k<<<BATCH * 4 * 8, 256, 0, stream>>>(xm, wsw, dsc, out);
}

// Round 5
// 348.082 us; speedup vs baseline: 1.7428x; 1.7428x over previous
//
#include <hip/hip_runtime.h>

#define IN_C 512
#define OUT_C 512
#define BATCH 16
#define NPX 4096   // 64*64

using bf16x8 = __attribute__((ext_vector_type(8))) __bf16;
using f32x4  = __attribute__((ext_vector_type(4))) float;

static constexpr float kConvScale = 0.014731391274719739f; // 1/sqrt(512*9)
static constexpr float kModScale  = 0.04419417382415922f;  // 1/sqrt(512)
static constexpr float kEps       = 1e-8f;

#define WT_TILE_BYTES (9 * 64 * 64)    // 36864 B per (ics, ot64) weight tile

// ---------- 1) s[b][ic] = style[b,:] . mod_weight[ic,:] * MOD_SCALE + mod_bias[ic]
__global__ void style_k(const float* __restrict__ style, const float* __restrict__ mw,
                        const float* __restrict__ mb, float* __restrict__ s) {
  __shared__ float st[IN_C];
  const int b = blockIdx.x, t = threadIdx.x;   // 512 threads
  st[t] = style[b * IN_C + t];
  __syncthreads();
  const float4* row = (const float4*)(mw + (size_t)t * IN_C);
  float acc = 0.f;
  #pragma unroll 4
  for (int i = 0; i < IN_C / 4; i++) {
    float4 v = row[i];
    float4 u = *(const float4*)(st + i * 4);
    acc += v.x * u.x + v.y * u.y + v.z * u.z + v.w * u.w;
  }
  s[b * IN_C + t] = acc * kModScale + mb[t];
}

// ---------- 2) wsq[oc][ic] = sum_tap w^2 ; wsw = bf16 weights, 64-oc-tile-major +
// XOR-swizzled. Tile (ics, ot64): logical byte B = (tap*64 + oc&63)*64 + icl*2,
// stored at B ^ (((B>>7)&7)<<4)  [(B>>7)&7 == ((oc&63)>>1)&7 since tap*32 % 8 == 0].
__global__ void wprep_k(const float* __restrict__ w, float* __restrict__ wsq,
                        char* __restrict__ wsw) {
  const int idx = blockIdx.x * 256 + threadIdx.x;  // 262144 total
  const int ic = idx & (IN_C - 1), oc = idx >> 9;
  const int ot = oc >> 6, ocl = oc & 63, ics = ic >> 5, icl = ic & 31;
  char* tile = wsw + (size_t)(ics * 8 + ot) * WT_TILE_BYTES;
  const float* p = w + (size_t)(oc * IN_C + ic) * 9;
  float q = 0.f;
  #pragma unroll
  for (int t = 0; t < 9; t++) {
    float v = p[t];
    q += v * v;
    int B = ((t * 64 + ocl) << 6) + icl * 2;
    int Bsw = B ^ (((B >> 7) & 7) << 4);
    *(__bf16*)(tile + Bsw) = (__bf16)v;
  }
  wsq[oc * IN_C + ic] = q;
}

// ---------- 3) dscale[b][oc] = CONV_SCALE * rsqrt(CONV_SCALE^2 * sum_ic s^2*wsq + eps)
__global__ void demod_k(const float* __restrict__ s, const float* __restrict__ wsq,
                        float* __restrict__ dsc) {
  __shared__ float s2[IN_C];
  const int b = blockIdx.x, t = threadIdx.x;   // 512 threads
  float sv = s[b * IN_C + t];
  s2[t] = sv * sv;
  __syncthreads();
  const float4* row = (const float4*)(wsq + (size_t)t * IN_C);
  float acc = 0.f;
  #pragma unroll 4
  for (int i = 0; i < IN_C / 4; i++) {
    float4 v = row[i];
    float4 u = *(const float4*)(s2 + i * 4);
    acc += v.x * u.x + v.y * u.y + v.z * u.z + v.w * u.w;
  }
  dsc[b * OUT_C + t] = kConvScale * rsqrtf(kConvScale * kConvScale * acc + kEps);
}

// ---------- 4) xmod[b][p][ic] = bf16(x[b][ic][p] * s[b][ic])   (NCHW -> NHWC transpose)
__global__ void modx_k(const float* __restrict__ x, const float* __restrict__ s,
                       __bf16* __restrict__ xm) {
  __shared__ __bf16 tile[64][73];
  const int t = threadIdx.x;                   // 256 threads
  const int bid = blockIdx.x;                  // 16 * 8 * 64
  const int ict = bid & 7, pt = (bid >> 3) & 63, b = bid >> 9;
  const int ic0 = ict * 64, p0 = pt * 64;
  #pragma unroll
  for (int it = 0; it < 16; it++) {
    int idx = it * 256 + t;
    int pl = idx & 63, icl = idx >> 6;
    int ic = ic0 + icl;
    float v = x[((size_t)b * IN_C + ic) * NPX + p0 + pl] * s[b * IN_C + ic];
    tile[icl][pl] = (__bf16)v;
  }
  __syncthreads();
  #pragma unroll
  for (int it = 0; it < 2; it++) {
    int idx = it * 256 + t;
    int icb = idx & 7, pl = idx >> 3;
    alignas(16) __bf16 tmp[8];
    #pragma unroll
    for (int j = 0; j < 8; j++) tmp[j] = tile[icb * 8 + j][pl];
    *(uint4*)(xm + ((size_t)b * NPX + p0 + pl) * IN_C + ic0 + icb * 8) = *(const uint4*)tmp;
  }
}

// ---------- 5) conv: NEW this round — TWO independent 4-wave blocks per CU.
// Block = 256 thr, tile 64 oc x 512 px; per-wave shape (64oc x 128px, acc[4][8],
// 9-tap pipeline, SGB interleave) is UNCHANGED from the 253-us round-0 kernel.
// Rationale: R0's 6K-cyc/step of exposed stage+drain came from ONE block-wide
// barrier stalling the whole CU at vmcnt(0). With two co-resident blocks
// (LDS 79104 B <= 80 KiB each) the barriers are independent: while one block
// drains its glds, the other block's waves keep the MFMA/LDS pipes busy
// (m114 co-scheduling). Per-wave register pressure identical to R0 (~110 arch
// VGPR + 128 AGPR) -> no spill (rounds 1/2/4 all died by spilling).
// x staged via global_load_lds into unpadded [10][66][32ic] (R4-verified
// addressing; unpadded is mandatory for glds linear dest). Weights per-64-oc
// tile, 9 glds/thread. Plain __syncthreads only; no asm waits, no sched_barrier.

#define XROW 4224              // 66 slots * 64 B (32 ic * 2 B), no pad

#define SGB __builtin_amdgcn_sched_group_barrier
// per tap: 12 DS_READ + 32 MFMA -> interleave {3 DS, 8 MFMA} x4 (R0 pattern)
#define SGB_MIX() { SGB(0x100, 3, 0); SGB(0x8, 8, 0); SGB(0x100, 3, 0); SGB(0x8, 8, 0); \
                    SGB(0x100, 3, 0); SGB(0x8, 8, 0); SGB(0x100, 3, 0); SGB(0x8, 8, 0); }
#define SGB_MFMA() { SGB(0x8, 8, 0); SGB(0x8, 8, 0); SGB(0x8, 8, 0); SGB(0x8, 8, 0); }

__global__ __launch_bounds__(256, 2)
void conv_k(const __bf16* __restrict__ xm, const char* __restrict__ wsw,
            const float* __restrict__ dsc, float* __restrict__ out) {
  __shared__ __align__(16) char xsb[10 * XROW];      // 42240 B input tile
  __shared__ __align__(16) char wsb[WT_TILE_BYTES];  // 36864 B weight tile
  // total 79104 B -> 2 blocks/CU

  const int tid = threadIdx.x;
  const int lane = tid & 63;
  const int wn = tid >> 6;                 // 4 waves = 4 px-quarters (128 px each)
  const int l15 = lane & 15, kb8 = lane >> 4;
  const int bid = blockIdx.x;
  const int pt = bid & 7, ot = (bid >> 3) & 7, b = bid >> 6;
  const int h0 = pt * 8, oc0 = ot * 64;

  // zero halo columns (slots 0 and 65), all 10 rows; never overwritten
  if (tid < 80) {
    int r = tid >> 3, side = (tid >> 2) & 1, ch = tid & 3;
    uint4 z = {0, 0, 0, 0};
    *(uint4*)(xsb + r * XROW + side * 65 * 64 + ch * 16) = z;
  }
  // zero halo rows for edge blocks (rows skipped by XGLDS stay zero all steps)
  if (h0 == 0) {
    uint4 z = {0, 0, 0, 0};
    for (int i = tid; i < 264; i += 256) ((uint4*)xsb)[i] = z;
  }
  if (h0 == 56) {
    uint4 z = {0, 0, 0, 0};
    for (int i = tid; i < 264; i += 256) ((uint4*)(xsb + 9 * XROW))[i] = z;
  }

  // ---- input staging: one glds per row; dest linear in tid (row interior = 4 KB);
  // source NHWC per-lane. h-guard is wave-uniform (r compile-time, h0 block-uniform).
  #define XGLDS(ICS)                                                          \
    {                                                                         \
      _Pragma("unroll")                                                       \
      for (int r = 0; r < 10; r++) {                                          \
        int h = h0 + r - 1;                                                   \
        if ((unsigned)h < 64u)                                                \
          __builtin_amdgcn_global_load_lds(                                   \
              (const __attribute__((address_space(1))) void*)(xm +            \
                  ((size_t)(b * 4096 + h * 64 + (tid >> 2))) * 512 +          \
                  (ICS) * 32 + (tid & 3) * 8),                                \
              (__attribute__((address_space(3))) void*)(xsb +                 \
                  r * XROW + 64 + tid * 16),                                  \
              16, 0, 0);                                                      \
      }                                                                       \
    }
  // ---- weight staging: 9 glds/thread (one tap each: 256 thr * 16 B = 4096 B = 1 tap)
  #define WGLDS(ICS)                                                          \
    {                                                                         \
      const char* wt = wsw + (size_t)((ICS) * 8 + ot) * WT_TILE_BYTES;        \
      _Pragma("unroll")                                                       \
      for (int g = 0; g < 9; g++) {                                           \
        int off = (g * 256 + tid) * 16;                                       \
        __builtin_amdgcn_global_load_lds(                                     \
            (const __attribute__((address_space(1))) void*)(wt + off),        \
            (__attribute__((address_space(3))) void*)(wsb + off), 16, 0, 0);  \
      }                                                                       \
    }

  f32x4 acc[4][8];
  #pragma unroll
  for (int i = 0; i < 4; i++)
    #pragma unroll
    for (int j = 0; j < 8; j++) acc[i][j] = f32x4{0.f, 0.f, 0.f, 0.f};

  // swizzled weight read address: oc_local = fm*16 + l15 (fm adds fm*1024 B);
  // swizzle mask depends only on (l15>>1)&7 (fm*8 % 8 == 0)
  const int swz = ((l15 >> 1) & 7) << 4;
  const int wrd_base = ((l15 << 6) + kb8 * 16) ^ swz;

  // tap-level fragment pipeline (R0 structure)
  bf16x8 afA[4], bfA[8], afB[4], bfB[8];
  #define LOADT(T, AF, BF)                                                    \
    {                                                                         \
      _Pragma("unroll")                                                       \
      for (int fm = 0; fm < 4; fm++)                                          \
        AF[fm] = *(const bf16x8*)(wsb + ((T) * 4096 + fm * 1024 + wrd_base)); \
      _Pragma("unroll")                                                       \
      for (int fn = 0; fn < 8; fn++) {                                        \
        int px = wn * 128 + fn * 16 + l15;                                    \
        BF[fn] = *(const bf16x8*)(xsb + ((px >> 6) + ((T) / 3)) * XROW +      \
                                  ((px & 63) + ((T) % 3)) * 64 + kb8 * 16);   \
      }                                                                       \
    }
  #define MFMAT(AF, BF)                                                       \
    {                                                                         \
      _Pragma("unroll")                                                       \
      for (int fm = 0; fm < 4; fm++)                                          \
        _Pragma("unroll")                                                     \
        for (int fn = 0; fn < 8; fn++)                                        \
          acc[fm][fn] = __builtin_amdgcn_mfma_f32_16x16x32_bf16(              \
              AF[fm], BF[fn], acc[fm][fn], 0, 0, 0);                          \
    }

  for (int s = 0; s < 16; s++) {
    __syncthreads();                       // (a) prev step's LDS reads consumed
    XGLDS(s)
    WGLDS(s)
    __syncthreads();                       // (b) drains glds -> x+w resident
    // (co-resident second block covers this block's stage/drain window)

    LOADT(0, afA, bfA)
    LOADT(1, afB, bfB)
    MFMAT(afA, bfA)  SGB_MIX()             // t0 (overlaps t1 loads issued above)
    LOADT(2, afA, bfA)
    MFMAT(afB, bfB)  SGB_MIX()             // t1 || load t2
    LOADT(3, afB, bfB)
    MFMAT(afA, bfA)  SGB_MIX()             // t2 || load t3
    LOADT(4, afA, bfA)
    MFMAT(afB, bfB)  SGB_MIX()             // t3 || load t4
    LOADT(5, afB, bfB)
    MFMAT(afA, bfA)  SGB_MIX()             // t4 || load t5
    LOADT(6, afA, bfA)
    MFMAT(afB, bfB)  SGB_MIX()             // t5 || load t6
    LOADT(7, afB, bfB)
    MFMAT(afA, bfA)  SGB_MIX()             // t6 || load t7
    LOADT(8, afA, bfA)
    MFMAT(afB, bfB)  SGB_MIX()             // t7 || load t8
    MFMAT(afA, bfA)  SGB_MFMA()            // t8
  }

  // epilogue: D row = oc_local (= fm*16 + kb8*4 + j), col = px (= wn*128 + fn*16 + l15)
  #pragma unroll
  for (int fm = 0; fm < 4; fm++) {
    #pragma unroll
    for (int j = 0; j < 4; j++) {
      int oc = oc0 + fm * 16 + kb8 * 4 + j;
      float dm = dsc[b * OUT_C + oc];
      float* orow = out + ((size_t)b * OUT_C + oc) * NPX + h0 * 64;
      #pragma unroll
      for (int fn = 0; fn < 8; fn++) {
        int px = wn * 128 + fn * 16 + l15;
        orow[px] = acc[fm][fn][j] * dm;
      }
    }
  }
}

extern "C" void kernel_launch(void* const* d_in, const int* in_sizes, int n_in,
                              void* d_out, int out_size, void* d_ws, size_t ws_size,
                              hipStream_t stream) {
  const float* input  = (const float*)d_in[0];
  const float* style  = (const float*)d_in[1];
  const float* weight = (const float*)d_in[2];
  const float* mod_w  = (const float*)d_in[3];
  const float* mod_b  = (const float*)d_in[4];
  float* out = (float*)d_out;

  char* p = (char*)d_ws;
  float* s    = (float*)p;  p += (size_t)BATCH * IN_C * 4;       // 32 KB
  float* dsc  = (float*)p;  p += (size_t)BATCH * OUT_C * 4;      // 32 KB
  float* wsq  = (float*)p;  p += (size_t)OUT_C * IN_C * 4;       // 1 MB
  char*  wsw  = p;          p += (size_t)16 * 8 * WT_TILE_BYTES; // 4.5 MB
  __bf16* xm  = (__bf16*)p;                                      // 64 MB

  style_k<<<BATCH, 512, 0, stream>>>(style, mod_w, mod_b, s);
  wprep_k<<<1024, 256, 0, stream>>>(weight, wsq, wsw);
  demod_k<<<BATCH, 512, 0, stream>>>(s, wsq, dsc);
  modx_k<<<BATCH * 8 * 64, 256, 0, stream>>>(input, s, xm);
  conv_k<<<BATCH * 8 * 8, 256, 0, stream>>>(xm, wsw, dsc, out);
}